// Round 14
// baseline (491.273 us; speedup 1.0000x reference)
//
#include <hip/hip_runtime.h>
#include <hip/hip_bf16.h>

#define ELq 4194304   // B*T*C
#define Cq 2048
#define Tq 1024
#define Hq 32
#define Mq 2048       // B*T
#define SBYTES 1536   // scanbuf bytes per (head, t) step-block
#define EBYTES 1664   // pairext bytes per (head, pair) block

typedef __attribute__((ext_vector_type(8))) short bf16x8;
typedef __attribute__((ext_vector_type(4))) float f32x4;

__device__ __forceinline__ unsigned short f2bu(float f) {
  union { float f; unsigned u; } v; v.f = f;
  unsigned r = v.u + 0x7fffu + ((v.u >> 16) & 1u);
  return (unsigned short)(r >> 16);
}
__device__ __forceinline__ float b2f(unsigned short u) {
  union { unsigned u; float f; } v; v.u = ((unsigned)u) << 16;
  return v.f;
}
__device__ __forceinline__ void gl_lds16(const void* g, void* l) {
  __builtin_amdgcn_global_load_lds((const __attribute__((address_space(1))) unsigned int*)g,
                                   (__attribute__((address_space(3))) unsigned int*)l, 16, 0, 0);
}

// DPP cross-lane add: x + lane-permuted x. VALU-pipe (no LDS), ~4-8 cyc.
template<int CTRL>
__device__ __forceinline__ float dpp_add(float x) {
  int t = __builtin_amdgcn_update_dpp(0, __builtin_bit_cast(int, x), CTRL, 0xF, 0xF, true);
  return x + __builtin_bit_cast(float, t);
}
// 16-lane sum broadcast (pure DPP, no LDS pipe)
__device__ __forceinline__ float red16(float x) {
  x = dpp_add<0xB1>(x); x = dpp_add<0x4E>(x);
  x = dpp_add<0x141>(x); x = dpp_add<0x140>(x);
  return x;
}

// scanbuf: per (head bh = b*32+h, t): 1536B block, all fp32
//   [0,256) r | [256,512) k | [512,768) a=-kk | [768,1024) b=kk*as
//   [1024,1280) w | [1280,1536) v
__device__ __forceinline__ size_t sb_off(int m, int c) {
  size_t blk = (size_t)(((m >> 10) * 32 + (c >> 6)) * 1024 + (m & 1023));
  return blk * SBYTES;
}

// ---------------- weight convert / transpose (+ scalar zero in block 0) ----------------
struct ConvJob { const float* src; unsigned short* dst; int rows, cols, trans; };
struct ConvJobs { ConvJob j[12]; unsigned int* scal; };

__global__ void k_conv(ConvJobs jobs) {
  if (blockIdx.z == 0 && blockIdx.x == 0 && threadIdx.x < 8) jobs.scal[threadIdx.x] = 0u;
  ConvJob jb = jobs.j[blockIdx.z];
  int n = jb.rows * jb.cols;
  if (!jb.trans) {
    int n4 = n >> 2;
    for (int i = blockIdx.x * blockDim.x + threadIdx.x; i < n4; i += gridDim.x * blockDim.x) {
      float4 v = ((const float4*)jb.src)[i];
      ushort4 o;
      o.x = f2bu(v.x); o.y = f2bu(v.y); o.z = f2bu(v.z); o.w = f2bu(v.w);
      ((ushort4*)jb.dst)[i] = o;
    }
  } else {
    for (int i = blockIdx.x * blockDim.x + threadIdx.x; i < n; i += gridDim.x * blockDim.x) {
      int col = i / jb.rows;
      int row = i - col * jb.rows;
      jb.dst[i] = f2bu(jb.src[(size_t)row * jb.cols + col]);
    }
  }
}

// ---------------- token shift prologue (float4 vectorized) ----------------
__global__ void k_prologue(const float* __restrict__ x,
    const float* __restrict__ mr, const float* __restrict__ mw, const float* __restrict__ mk,
    const float* __restrict__ mv, const float* __restrict__ ma, const float* __restrict__ mg,
    unsigned short* __restrict__ xr, unsigned short* __restrict__ xw, unsigned short* __restrict__ xk,
    unsigned short* __restrict__ xv, unsigned short* __restrict__ xa, unsigned short* __restrict__ xg)
{
  int i4 = blockIdx.x * 256 + threadIdx.x;
  if (i4 >= ELq / 4) return;
  int i = i4 << 2;
  float4 xc = *(const float4*)(x + i);
  int t = (i >> 11) & (Tq - 1);
  float4 xp = make_float4(0.f, 0.f, 0.f, 0.f);
  if (t) xp = *(const float4*)(x + i - Cq);
  float4 dx = make_float4(xp.x - xc.x, xp.y - xc.y, xp.z - xc.z, xp.w - xc.w);
  int c = i & (Cq - 1);
  auto mix = [&](const float* __restrict__ m, unsigned short* __restrict__ o) {
    float4 mm = *(const float4*)(m + c);
    ushort4 u;
    u.x = f2bu(xc.x + dx.x * mm.x); u.y = f2bu(xc.y + dx.y * mm.y);
    u.z = f2bu(xc.z + dx.z * mm.z); u.w = f2bu(xc.w + dx.w * mm.w);
    *(ushort4*)(o + i) = u;
  };
  mix(mr, xr); mix(mw, xw); mix(mk, xk); mix(mv, xv); mix(ma, xa); mix(mg, xg);
}

// ---------------- GEMM (A MxK row-major bf16, B NxK row-major bf16; C = A*B^T) ----------------
struct GJob {
  const unsigned short* A; const unsigned short* B;
  const float* bias; float* Cf; unsigned short* Cb;
  unsigned int* amax; const float* aux;
  int K; int ld; int epi;
  const float* kkw; const float* kaw; const float* asig;
  unsigned char* scan;
};
struct GJobs { GJob j[4]; };

// epi: 0 f32 | 1 f32+bias | 2 f32 sigmoid(v+bias) | 4 bf16 | 7 f32+absmax
//      9 v->scan+absmax(aux-v) | 10 w-decay->scan | 11 k-prep->scan | 12 r->scan
__device__ __forceinline__ void epi_store(int epi, float v, size_t o,
    float* Cf, unsigned short* Cb, const float* bias, int col, float& lmax)
{
  switch (epi) {
    case 0: Cf[o] = v; break;
    case 1: Cf[o] = v + bias[col]; break;
    case 2: Cf[o] = 1.f / (1.f + expf(-(v + bias[col]))); break;
    case 4: Cb[o] = f2bu(v); break;
    case 7: lmax = fmaxf(lmax, fabsf(v)); Cf[o] = v; break;
  }
}

// BK=64 via twin ping-pong [128][32] buffers.
__global__ __launch_bounds__(256, 2) void k_gemm128(GJobs jobs) {
  GJob jb = jobs.j[blockIdx.z];
  __shared__ __align__(16) unsigned short As[2][128 * 32];
  __shared__ __align__(16) unsigned short Bs[2][128 * 32];
  __shared__ float sred[4];
  const int tid = threadIdx.x, lane = tid & 63, wid = tid >> 6;
  const int wr = wid >> 1, wc = wid & 1;
  const int lin = blockIdx.y * 16 + blockIdx.x;
  const int swz = (lin & 7) * 32 + (lin >> 3);
  const int m0 = (swz >> 4) * 128, n0 = (swz & 15) * 128;
  const int K = jb.K, ld = jb.ld;
  const unsigned short* A = jb.A; const unsigned short* B = jb.B;
  f32x4 acc[4][4] = {};
  const int stg_row = (wid * 64 + lane) >> 2;
  const int stg_q   = lane & 3;
  const int stg_row2 = stg_row + 64;
  for (int k0 = 0; k0 < K; k0 += 64) {
    const bool h2 = (k0 + 32 < K);
    {
      int cw0 = wid * 64, cw1 = wid * 64 + 256;
      gl_lds16(A + (size_t)(m0 + stg_row) * ld + k0 + stg_q * 8, &As[0][cw0 * 8]);
      gl_lds16(B + (size_t)(n0 + stg_row) * ld + k0 + stg_q * 8, &Bs[0][cw0 * 8]);
      gl_lds16(A + (size_t)(m0 + stg_row2) * ld + k0 + stg_q * 8, &As[0][cw1 * 8]);
      gl_lds16(B + (size_t)(n0 + stg_row2) * ld + k0 + stg_q * 8, &Bs[0][cw1 * 8]);
      if (h2) {
        gl_lds16(A + (size_t)(m0 + stg_row) * ld + k0 + 32 + stg_q * 8, &As[1][cw0 * 8]);
        gl_lds16(B + (size_t)(n0 + stg_row) * ld + k0 + 32 + stg_q * 8, &Bs[1][cw0 * 8]);
        gl_lds16(A + (size_t)(m0 + stg_row2) * ld + k0 + 32 + stg_q * 8, &As[1][cw1 * 8]);
        gl_lds16(B + (size_t)(n0 + stg_row2) * ld + k0 + 32 + stg_q * 8, &Bs[1][cw1 * 8]);
      }
    }
    __syncthreads();
    const int kg = (lane >> 4) * 8;
    bf16x8 af[4], bq[4];
    #pragma unroll
    for (int mi = 0; mi < 4; ++mi)
      af[mi] = *(const bf16x8*)&As[0][(wr * 64 + mi * 16 + (lane & 15)) * 32 + kg];
    #pragma unroll
    for (int ni = 0; ni < 4; ++ni)
      bq[ni] = *(const bf16x8*)&Bs[0][(wc * 64 + ni * 16 + (lane & 15)) * 32 + kg];
    #pragma unroll
    for (int mi = 0; mi < 4; ++mi)
      #pragma unroll
      for (int ni = 0; ni < 4; ++ni)
        acc[mi][ni] = __builtin_amdgcn_mfma_f32_16x16x32_bf16(af[mi], bq[ni], acc[mi][ni], 0, 0, 0);
    if (h2) {
      #pragma unroll
      for (int mi = 0; mi < 4; ++mi)
        af[mi] = *(const bf16x8*)&As[1][(wr * 64 + mi * 16 + (lane & 15)) * 32 + kg];
      #pragma unroll
      for (int ni = 0; ni < 4; ++ni)
        bq[ni] = *(const bf16x8*)&Bs[1][(wc * 64 + ni * 16 + (lane & 15)) * 32 + kg];
      #pragma unroll
      for (int mi = 0; mi < 4; ++mi)
        #pragma unroll
        for (int ni = 0; ni < 4; ++ni)
          acc[mi][ni] = __builtin_amdgcn_mfma_f32_16x16x32_bf16(af[mi], bq[ni], acc[mi][ni], 0, 0, 0);
    }
    __syncthreads();
  }
  if (jb.epi == 12) {          // r -> scanbuf f32 @ +0
    #pragma unroll
    for (int mi = 0; mi < 4; ++mi)
      #pragma unroll
      for (int ni = 0; ni < 4; ++ni) {
        int col = n0 + wc * 64 + ni * 16 + (lane & 15);
        int row0 = m0 + wr * 64 + mi * 16 + ((lane >> 4) << 2);
        #pragma unroll
        for (int q = 0; q < 4; ++q)
          *(float*)(jb.scan + sb_off(row0 + q, col) + ((col & 63) << 2)) = acc[mi][ni][q];
      }
    return;
  }
  if (jb.epi == 10) {          // w decay -> scanbuf f32 @ +1024
    #pragma unroll
    for (int mi = 0; mi < 4; ++mi)
      #pragma unroll
      for (int ni = 0; ni < 4; ++ni) {
        int col = n0 + wc * 64 + ni * 16 + (lane & 15);
        int row0 = m0 + wr * 64 + mi * 16 + ((lane >> 4) << 2);
        float bc = jb.bias[col];
        #pragma unroll
        for (int q = 0; q < 4; ++q) {
          float wv = acc[mi][ni][q] + bc;
          float wlog = -log1pf(expf(-wv)) - 0.5f;
          *(float*)(jb.scan + sb_off(row0 + q, col) + 1024 + ((col & 63) << 2)) =
              expf(-expf(wlog));
        }
      }
    return;
  }
  if (jb.epi == 11) {          // k-prep -> scanbuf f32 (k@+256, -kk@+512, kk*as@+768)
    float kkwv[4], kawv[4]; int colv[4];
    #pragma unroll
    for (int ni = 0; ni < 4; ++ni) {
      colv[ni] = n0 + wc * 64 + ni * 16 + (lane & 15);
      kkwv[ni] = jb.kkw[colv[ni]];
      kawv[ni] = jb.kaw[colv[ni]];
    }
    #pragma unroll
    for (int mi = 0; mi < 4; ++mi) {
      #pragma unroll
      for (int q = 0; q < 4; ++q) {
        float kkv[4]; float ss = 0.f;
        #pragma unroll
        for (int ni = 0; ni < 4; ++ni) {
          kkv[ni] = acc[mi][ni][q] * kkwv[ni];
          ss += kkv[ni] * kkv[ni];
        }
        ss = red16(ss);
        float inv = 1.f / fmaxf(sqrtf(ss), 1e-12f);
        int row = m0 + wr * 64 + mi * 16 + ((lane >> 4) << 2) + q;
        #pragma unroll
        for (int ni = 0; ni < 4; ++ni) {
          int col = colv[ni];
          unsigned char* base = jb.scan + sb_off(row, col);
          int n4 = (col & 63) << 2;
          float kraw = acc[mi][ni][q];
          float kkn = kkv[ni] * inv;
          float as = jb.asig[(size_t)row * 2048 + col];
          *(float*)(base + 256 + n4) = kraw * (1.f + (as - 1.f) * kawv[ni]);
          *(float*)(base + 512 + n4) = -kkn;
          *(float*)(base + 768 + n4) = kkn * as;
        }
      }
    }
    return;
  }
  float lmax = 0.f;
  if (jb.epi == 9) {           // v raw -> scanbuf f32 @ +1280, absmax(aux - v)
    #pragma unroll
    for (int mi = 0; mi < 4; ++mi)
      #pragma unroll
      for (int ni = 0; ni < 4; ++ni) {
        int col = n0 + wc * 64 + ni * 16 + (lane & 15);
        int row0 = m0 + wr * 64 + mi * 16 + ((lane >> 4) << 2);
        #pragma unroll
        for (int q = 0; q < 4; ++q) {
          float v = acc[mi][ni][q];
          lmax = fmaxf(lmax, fabsf(jb.aux[(size_t)(row0 + q) * 2048 + col] - v));
          *(float*)(jb.scan + sb_off(row0 + q, col) + 1280 + ((col & 63) << 2)) = v;
        }
      }
  } else {
    #pragma unroll
    for (int mi = 0; mi < 4; ++mi)
      #pragma unroll
      for (int ni = 0; ni < 4; ++ni) {
        int col = n0 + wc * 64 + ni * 16 + (lane & 15);
        int row = m0 + wr * 64 + mi * 16 + ((lane >> 4) << 2);
        #pragma unroll
        for (int q = 0; q < 4; ++q)
          epi_store(jb.epi, acc[mi][ni][q], (size_t)(row + q) * 2048 + col,
                    jb.Cf, jb.Cb, jb.bias, col, lmax);
      }
  }
  if (jb.epi == 7 || jb.epi == 9) {
    #pragma unroll
    for (int o = 32; o; o >>= 1) lmax = fmaxf(lmax, __shfl_xor(lmax, o));
    if (lane == 0) sred[wid] = lmax;
    __syncthreads();
    if (tid == 0)
      atomicMax(jb.amax, __float_as_uint(fmaxf(fmaxf(sred[0], sred[1]), fmaxf(sred[2], sred[3]))));
  }
}

// ---------------- skinny GEMMs, split-K x8, ALL FOUR in one dispatch ----------------
template<int TBN>
__device__ __forceinline__ void sk_body(const GJob& jb,
    unsigned short* __restrict__ As, unsigned short* __restrict__ Bs) {
  const int tid = threadIdx.x, lane = tid & 63, wid = tid >> 6;
  const int m0 = blockIdx.x * 128;
  const int koff = blockIdx.y * 256;
  const int ld = jb.ld;
  constexpr int NF = TBN / 16;
  const unsigned short* A = jb.A + koff;
  const unsigned short* B = jb.B + koff;
  float* out = jb.Cf + (size_t)blockIdx.y * (2048 * TBN);
  f32x4 acc[2][NF] = {};
  for (int k0 = 0; k0 < 256; k0 += 32) {
    for (int cw = wid * 64; cw < 512; cw += 256) {
      int c = cw + lane; int row = c >> 2, q = c & 3;
      gl_lds16(A + (size_t)(m0 + row) * ld + k0 + q * 8, &As[cw * 8]);
    }
    for (int cw = wid * 64; cw < TBN * 4; cw += 256) {
      int c = cw + lane; int row = c >> 2, q = c & 3;
      gl_lds16(B + (size_t)row * ld + k0 + q * 8, &Bs[cw * 8]);
    }
    __syncthreads();
    const int kg = (lane >> 4) * 8;
    bf16x8 af[2], bq[NF];
    #pragma unroll
    for (int mi = 0; mi < 2; ++mi)
      af[mi] = *(const bf16x8*)&As[(wid * 32 + mi * 16 + (lane & 15)) * 32 + kg];
    #pragma unroll
    for (int ni = 0; ni < NF; ++ni)
      bq[ni] = *(const bf16x8*)&Bs[(ni * 16 + (lane & 15)) * 32 + kg];
    #pragma unroll
    for (int mi = 0; mi < 2; ++mi)
      #pragma unroll
      for (int ni = 0; ni < NF; ++ni)
        acc[mi][ni] = __builtin_amdgcn_mfma_f32_16x16x32_bf16(af[mi], bq[ni], acc[mi][ni], 0, 0, 0);
    __syncthreads();
  }
  #pragma unroll
  for (int mi = 0; mi < 2; ++mi)
    #pragma unroll
    for (int ni = 0; ni < NF; ++ni) {
      int col = ni * 16 + (lane & 15);
      int row = m0 + wid * 32 + mi * 16 + ((lane >> 4) << 2);
      #pragma unroll
      for (int q = 0; q < 4; ++q)
        out[(size_t)(row + q) * TBN + col] = acc[mi][ni][q];
    }
}

__global__ __launch_bounds__(256, 2) void k_skinny(GJobs jobs) {
  __shared__ __align__(16) unsigned short As[128 * 32];
  __shared__ __align__(16) unsigned short Bs[128 * 32];
  switch (blockIdx.z) {
    case 0:  sk_body<64>(jobs.j[0], As, Bs); break;
    case 1:  sk_body<64>(jobs.j[1], As, Bs); break;
    case 2:  sk_body<32>(jobs.j[2], As, Bs); break;
    default: sk_body<128>(jobs.j[3], As, Bs); break;
  }
}

// ---------------- split-K reduce + activations for the 4 skinny GEMMs ----------------
__global__ void k_skepi(const float* __restrict__ pw, const float* __restrict__ pa,
                        const float* __restrict__ pv, const float* __restrict__ pg,
                        unsigned short* __restrict__ hw, unsigned short* __restrict__ ha,
                        unsigned short* __restrict__ hv, unsigned short* __restrict__ hg,
                        unsigned int* __restrict__ amax) {
  int i = blockIdx.x * 256 + threadIdx.x;    // 0 .. 589823
  const float* src; unsigned short* dst; int stride, mode, loc;
  if (i < 131072)      { src = pw; dst = hw; stride = 131072; mode = 0; loc = i; }
  else if (i < 262144) { src = pa; dst = ha; stride = 131072; mode = 1; loc = i - 131072; }
  else if (i < 327680) { src = pv; dst = hv; stride = 65536;  mode = 2; loc = i - 262144; }
  else                 { src = pg; dst = hg; stride = 262144; mode = 3; loc = i - 327680; }
  float s = 0.f;
  #pragma unroll
  for (int sp = 0; sp < 8; ++sp) s += src[loc + (size_t)sp * stride];
  float lmax = 0.f, o;
  switch (mode) {
    case 0: o = tanhf(s); break;
    case 1: o = s; break;
    case 2: o = s; lmax = fabsf(s); break;
    default: o = 1.f / (1.f + expf(-s)); break;
  }
  dst[loc] = f2bu(o);
  #pragma unroll
  for (int of = 32; of; of >>= 1) lmax = fmaxf(lmax, __shfl_xor(lmax, of));
  if ((threadIdx.x & 63) == 0 && lmax > 0.f) atomicMax(amax, __float_as_uint(lmax));
}

// ---------------- v residual gating, IN PLACE on scanbuf @ +1280 ----------------
__global__ void k_vfin(const float* __restrict__ vf, const float* __restrict__ z,
                       const float* __restrict__ v0c, const unsigned int* __restrict__ sc,
                       unsigned char* __restrict__ scan) {
  int i4 = blockIdx.x * 256 + threadIdx.x;
  if (i4 >= ELq / 4) return;
  int i = i4 << 2;
  float m1 = fmaxf(__uint_as_float(sc[0]), 1.f);
  float m2 = fmaxf(__uint_as_float(sc[1]) / m1, 1.f);
  float inv12 = 1.f / (m1 * m2);
  float invvd = 1.f / fmaxf(__uint_as_float(sc[2]), 1.f);
  int m = i >> 11;
  int c = i & (Cq - 1);
  float* vp = (float*)(scan + sb_off(m, c) + 1280 + ((c & 63) << 2));
  float4 zv = *(const float4*)(z + i);
  float4 vv = *(const float4*)vp;
  float4 fv = *(const float4*)(vf + i);
  float4 v0v = *(const float4*)(v0c + c);
  float4 o;
  #pragma unroll
  for (int j = 0; j < 4; ++j) {
    float gx = (&v0v.x)[j] + (&zv.x)[j] * inv12;
    gx = fminf(fmaxf(gx, -16.f), 16.f);
    float gate = 1.f / (1.f + expf(-gx));
    float vr = (&vv.x)[j];
    (&o.x)[j] = vr + ((&fv.x)[j] - vr) * (gate * invvd);
  }
  *(float4*)vp = o;
}

// ---------------- pair precompute: fuse 2 scan steps into one (parallel pass) ----
// S2 = S.W' + (S.a1)(x)beta1 + (S.alf2)(x)b2 + v1(x)kap1 + v2(x)k2
//   W'=w1w2, beta1=b1w2+(b1.a2)b2, alf2=w1a2, kap1=k1w2+(k1.a2)b2
// y1 = S.rho1 + (k1.r1)v1,  rho1 = w1r1+(b1.r1)a1
// y2 = S.rho2 + (kap1.r2)v1 + (k2.r2)v2, rho2 = W'r2+(beta1.r2)a1+(b2.r2)alf2
// ext block (1664B): alf2@0 beta1@256 kap1@512 W'@768 rho1@1024 rho2@1280
//   scalars@1536: [k1.r1, kap1.r2, k2.r2]
__global__ __launch_bounds__(256) void k_pre2(const unsigned char* __restrict__ scan,
                                              unsigned char* __restrict__ ext) {
  const int wv = threadIdx.x >> 6, j = threadIdx.x & 63;
  const int item = blockIdx.x * 4 + wv;        // bh*512 + p
  const int bh = item >> 9, p = item & 511;
  const unsigned char* L1 = scan + ((size_t)bh * 1024 + 2 * p) * SBYTES;
  const unsigned char* L2 = L1 + SBYTES;
  auto ldf = [&](const unsigned char* b, int off) {
    return *(const float*)(b + off + j * 4);
  };
  float r1 = ldf(L1, 0), k1 = ldf(L1, 256), a1 = ldf(L1, 512), b1 = ldf(L1, 768), w1 = ldf(L1, 1024);
  float r2 = ldf(L2, 0), k2 = ldf(L2, 256), a2 = ldf(L2, 512), b2 = ldf(L2, 768), w2 = ldf(L2, 1024);
  auto rsum = [](float x) {
    #pragma unroll
    for (int o = 32; o; o >>= 1) x += __shfl_xor(x, o);
    return x;
  };
  float d_b1a2 = rsum(b1 * a2);
  float d_k1a2 = rsum(k1 * a2);
  float d_b1r1 = rsum(b1 * r1);
  float d_k1r1 = rsum(k1 * r1);
  float d_b2r2 = rsum(b2 * r2);
  float d_k2r2 = rsum(k2 * r2);
  float beta = b1 * w2 + d_b1a2 * b2;
  float kap  = k1 * w2 + d_k1a2 * b2;
  float alf  = w1 * a2;
  float Wp   = w1 * w2;
  float rho1 = w1 * r1 + d_b1r1 * a1;
  float d_br2 = rsum(beta * r2);
  float d_kr2 = rsum(kap * r2);
  float rho2 = Wp * r2 + d_br2 * a1 + d_b2r2 * alf;
  unsigned char* E = ext + (size_t)item * EBYTES;
  *(float*)(E + 0    + j * 4) = alf;
  *(float*)(E + 256  + j * 4) = beta;
  *(float*)(E + 512  + j * 4) = kap;
  *(float*)(E + 768  + j * 4) = Wp;
  *(float*)(E + 1024 + j * 4) = rho1;
  *(float*)(E + 1280 + j * 4) = rho2;
  if (j == 0) {
    float* s = (float*)(E + 1536);
    s[0] = d_k1r1; s[1] = d_kr2; s[2] = d_k2r2; s[3] = 0.f;
  }
}

// ---------------- wkv7 scan: 2 tokens per fused step ------------------------------
// Block = 4 rows of one head (1024 blocks). lane: row = rq*4 + (lane>>4),
// elems [(lane&15)*4, +4). Per pair: 4 S-dots on the SAME old S -> 4 independent
// DPP chains pipeline; one S update per 2 tokens. 12 loads/pair (legacy + ext).
// Prefetch depth 4 via named buffers, unroll x4. bh = blk&63 -> same-head L2/XCD.
struct SR2 { float4 a1, al, p1, p2, be, b2, ka, k2, Wp, sc; float v1, v2; };

__device__ __forceinline__ void ld2(SR2& R, const unsigned char* L1,
                                    const unsigned char* E, int cl16, int row) {
  R.a1 = *(const float4*)(L1 + 512 + cl16);
  R.k2 = *(const float4*)(L1 + SBYTES + 256 + cl16);
  R.b2 = *(const float4*)(L1 + SBYTES + 768 + cl16);
  R.v1 = *(const float*)(L1 + 1280 + row * 4);
  R.v2 = *(const float*)(L1 + SBYTES + 1280 + row * 4);
  R.al = *(const float4*)(E + 0    + cl16);
  R.be = *(const float4*)(E + 256  + cl16);
  R.ka = *(const float4*)(E + 512  + cl16);
  R.Wp = *(const float4*)(E + 768  + cl16);
  R.p1 = *(const float4*)(E + 1024 + cl16);
  R.p2 = *(const float4*)(E + 1280 + cl16);
  R.sc = *(const float4*)(E + 1536);
}

__device__ __forceinline__ float dot4(const float S[4], float4 v) {
  return (S[0] * v.x + S[1] * v.y) + (S[2] * v.z + S[3] * v.w);
}

__device__ __forceinline__ void wkv_step2(const SR2& R, float S[4], float& ymx,
    float* __restrict__ y, size_t yoff, int lane) {
  float sa1 = red16(dot4(S, R.a1));
  float sa2 = red16(dot4(S, R.al));
  float yr1 = red16(dot4(S, R.p1));
  float yr2 = red16(dot4(S, R.p2));
  float y1 = yr1 + R.sc.x * R.v1;
  float y2 = yr2 + R.sc.y * R.v1 + R.sc.z * R.v2;
  S[0] = S[0] * R.Wp.x + sa1 * R.be.x + sa2 * R.b2.x + R.v1 * R.ka.x + R.v2 * R.k2.x;
  S[1] = S[1] * R.Wp.y + sa1 * R.be.y + sa2 * R.b2.y + R.v1 * R.ka.y + R.v2 * R.k2.y;
  S[2] = S[2] * R.Wp.z + sa1 * R.be.z + sa2 * R.b2.z + R.v1 * R.ka.z + R.v2 * R.k2.z;
  S[3] = S[3] * R.Wp.w + sa1 * R.be.w + sa2 * R.b2.w + R.v1 * R.ka.w + R.v2 * R.k2.w;
  if ((lane & 15) == 0) {
    y[yoff] = y1;
    y[yoff + Cq] = y2;
    ymx = fmaxf(ymx, fmaxf(fabsf(y1), fabsf(y2)));
  }
}

__global__ __launch_bounds__(64, 1) void k_wkv(const unsigned char* __restrict__ scan,
    const unsigned char* __restrict__ ext,
    float* __restrict__ y, unsigned int* __restrict__ ymax) {
  const int lane = threadIdx.x;
  const int bh = blockIdx.x & 63;          // b*32 + h — same-head blocks share an XCD
  const int rq = blockIdx.x >> 6;          // row quad (0..15)
  const int row = rq * 4 + (lane >> 4);
  const int cl16 = (lane & 15) * 16;
  float S[4];
  #pragma unroll
  for (int q = 0; q < 4; ++q) S[q] = 0.f;
  const unsigned char* gs = scan + (size_t)bh * Tq * SBYTES;
  const unsigned char* ge = ext + (size_t)bh * 512 * EBYTES;
  const size_t ybase = (size_t)(bh >> 5) * Tq * Cq + (size_t)(bh & 31) * 64 + row;

  SR2 R0, R1, R2, R3;
  ld2(R0, gs,                      ge,              cl16, row);
  ld2(R1, gs + 2 * SBYTES,         ge + EBYTES,     cl16, row);
  ld2(R2, gs + 4 * SBYTES,         ge + 2 * EBYTES, cl16, row);
  ld2(R3, gs + 6 * SBYTES,         ge + 3 * EBYTES, cl16, row);

  float ymx = 0.f;
  for (int p = 0; p < 512; p += 4) {
    int n0 = (p + 4 < 512) ? p + 4 : 511;
    int n1 = (p + 5 < 512) ? p + 5 : 511;
    int n2 = (p + 6 < 512) ? p + 6 : 511;
    int n3 = (p + 7 < 512) ? p + 7 : 511;
    wkv_step2(R0, S, ymx, y, ybase + (size_t)(2 * p) * Cq, lane);
    ld2(R0, gs + (size_t)(2 * n0) * SBYTES, ge + (size_t)n0 * EBYTES, cl16, row);
    wkv_step2(R1, S, ymx, y, ybase + (size_t)(2 * p + 2) * Cq, lane);
    ld2(R1, gs + (size_t)(2 * n1) * SBYTES, ge + (size_t)n1 * EBYTES, cl16, row);
    wkv_step2(R2, S, ymx, y, ybase + (size_t)(2 * p + 4) * Cq, lane);
    ld2(R2, gs + (size_t)(2 * n2) * SBYTES, ge + (size_t)n2 * EBYTES, cl16, row);
    wkv_step2(R3, S, ymx, y, ybase + (size_t)(2 * p + 6) * Cq, lane);
    ld2(R3, gs + (size_t)(2 * n3) * SBYTES, ge + (size_t)n3 * EBYTES, cl16, row);
  }
  #pragma unroll
  for (int o = 32; o; o >>= 1) ymx = fmaxf(ymx, __shfl_xor(ymx, o));
  if (lane == 0) atomicMax(ymax, __float_as_uint(ymx));
}

// ---------------- groupnorm + bonus + gate ----------------
__global__ __launch_bounds__(256) void k_epi1(const float* __restrict__ y,
    const unsigned char* __restrict__ scan, const unsigned short* __restrict__ g,
    const float* __restrict__ lnw, const float* __restrict__ lnb, const float* __restrict__ rk,
    unsigned short* __restrict__ yg) {
  int wid = threadIdx.x >> 6, lane = threadIdx.x & 63;
  int idx = blockIdx.x * 4 + wid;            // (b*Tq + t)*32 + h
  size_t off = (size_t)idx * 64 + lane;
  int c = ((idx & (Hq - 1)) << 6) | lane;
  int b = idx >> 15, t = (idx >> 5) & 1023, h = idx & 31;
  const unsigned char* so = scan + (size_t)((b * 32 + h) * 1024 + t) * SBYTES;
  float yv = y[off];
  float s = yv;
  #pragma unroll
  for (int o = 32; o; o >>= 1) s += __shfl_xor(s, o);
  float mu = s * (1.f / 64.f);
  float d = yv - mu;
  float vs = d * d;
  #pragma unroll
  for (int o = 32; o; o >>= 1) vs += __shfl_xor(vs, o);
  float yn = d / sqrtf(vs * (1.f / 64.f) + 6.4e-4f);
  float yo = yn * lnw[c] + lnb[c];
  float rv = *(const float*)(so + lane * 4);
  float kv = *(const float*)(so + 256 + lane * 4);
  float vv = *(const float*)(so + 1280 + lane * 4);
  float bon = rv * kv * rk[c];
  #pragma unroll
  for (int o = 32; o; o >>= 1) bon += __shfl_xor(bon, o);
  yo += bon * vv;
  yg[off] = f2bu(yo * b2f(g[off]));
}

// ---------------- fused finish: yout = (p0+p1)*scale ; vfout = vf*scale ----------------
__global__ void k_fin(const float* __restrict__ p0, const float* __restrict__ p1,
                      const unsigned int* __restrict__ sc, float* __restrict__ yout,
                      const float* __restrict__ vf, float* __restrict__ vfout) {
  int i = blockIdx.x * 256 + threadIdx.x;
  float s = (__uint_as_float(sc[3]) > 179.2f) ? 0.5f : 1.f;
  if (i < ELq / 4) {
    float4 a = ((const float4*)p0)[i];
    float4 b = ((const float4*)p1)[i];
    ((float4*)yout)[i] = make_float4((a.x + b.x) * s, (a.y + b.y) * s,
                                     (a.z + b.z) * s, (a.w + b.w) * s);
  } else {
    int j = i - ELq / 4;
    float4 vv = ((const float4*)vf)[j];
    ((float4*)vfout)[j] = make_float4(vv.x * s, vv.y * s, vv.z * s, vv.w * s);
  }
}

extern "C" void kernel_launch(void* const* d_in, const int* in_sizes, int n_in,
                              void* d_out, int out_size, void* d_ws, size_t ws_size,
                              hipStream_t stream) {
  const float* x      = (const float*)d_in[0];
  const float* vfirst = (const float*)d_in[1];
  const float* x_r = (const float*)d_in[2];
  const float* x_w = (const float*)d_in[3];
  const float* x_k = (const float*)d_in[4];
  const float* x_v = (const float*)d_in[5];
  const float* x_a = (const float*)d_in[6];
  const float* x_g = (const float*)d_in[7];
  const float* w0 = (const float*)d_in[8];
  const float* w1 = (const float*)d_in[9];
  const float* w2 = (const float*)d_in[10];
  const float* a0 = (const float*)d_in[11];
  const float* a1 = (const float*)d_in[12];
  const float* a2 = (const float*)d_in[13];
  const float* v0 = (const float*)d_in[14];
  const float* v1 = (const float*)d_in[15];
  const float* v2 = (const float*)d_in[16];
  const float* g1 = (const float*)d_in[17];
  const float* g2 = (const float*)d_in[18];
  const float* k_k = (const float*)d_in[19];
  const float* k_a = (const float*)d_in[20];
  const float* r_k = (const float*)d_in[21];
  const float* W_r = (const float*)d_in[22];
  const float* W_k = (const float*)d_in[23];
  const float* W_v = (const float*)d_in[24];
  const float* W_o = (const float*)d_in[25];
  const float* lnw = (const float*)d_in[26];
  const float* lnb = (const float*)d_in[27];

  char* ws = (char*)d_ws;
  size_t off = 0;
  auto alloc = [&](size_t bytes) -> void* {
    void* p = ws + off; off += (bytes + 255) & ~(size_t)255; return p;
  };
  unsigned int* scal = (unsigned int*)alloc(256);      // [M1, MZ, MVD, MY]
  unsigned char* scanbuf = (unsigned char*)alloc((size_t)64 * Tq * SBYTES);  // 96MB
  // pWo region (xrb..gbuf, 32MB) — dead-buffer aliases below are order-sensitive.
  unsigned short* xrb = (unsigned short*)alloc((size_t)ELq * 2);
  unsigned short* xab = (unsigned short*)alloc((size_t)ELq * 2);
  unsigned short* xgb = (unsigned short*)alloc((size_t)ELq * 2);
  unsigned short* gbuf = (unsigned short*)alloc((size_t)ELq * 2);
  unsigned short* ygb  = (unsigned short*)alloc((size_t)ELq * 2);
  unsigned short* WoB = (unsigned short*)alloc((size_t)ELq * 2);
  unsigned short* w1T = (unsigned short*)alloc(64 * 2048 * 2);
  unsigned short* a1T = (unsigned short*)alloc(64 * 2048 * 2);
  unsigned short* v1T = (unsigned short*)alloc(32 * 2048 * 2);
  unsigned short* g1T = (unsigned short*)alloc(128 * 2048 * 2);
  unsigned short* w2T = (unsigned short*)alloc(2048 * 64 * 2);
  unsigned short* a2T = (unsigned short*)alloc(2048 * 64 * 2);
  unsigned short* v2T = (unsigned short*)alloc(2048 * 32 * 2);
  unsigned short* g2T = (unsigned short*)alloc(2048 * 128 * 2);
  unsigned short* hwb = (unsigned short*)alloc((size_t)Mq * 64 * 2);
  unsigned short* hab = (unsigned short*)alloc((size_t)Mq * 64 * 2);
  unsigned short* hvb = (unsigned short*)alloc((size_t)Mq * 32 * 2);
  unsigned short* hgb = (unsigned short*)alloc((size_t)Mq * 128 * 2);
  // REGION_P — everything below dead after the r/k/v GEMM; pairext aliases it.
  unsigned short* xwb = (unsigned short*)alloc((size_t)ELq * 2);
  unsigned short* xkb = (unsigned short*)alloc((size_t)ELq * 2);
  unsigned short* xvb = (unsigned short*)alloc((size_t)ELq * 2);
  unsigned short* WrB = (unsigned short*)alloc((size_t)ELq * 2);
  unsigned short* WkB = (unsigned short*)alloc((size_t)ELq * 2);
  unsigned short* WvB = (unsigned short*)alloc((size_t)ELq * 2);
  float* pskw = (float*)alloc((size_t)8 * Mq * 64 * 4);
  float* pska = (float*)alloc((size_t)8 * Mq * 64 * 4);
  float* pskv = (float*)alloc((size_t)8 * Mq * 32 * 4);
  float* pskg = (float*)alloc((size_t)8 * Mq * 128 * 4);
  // Aliases (dead-buffer reuse, stream-order checked):
  float* abuf = pskw;                 // sigmoid-a: written by z4 GEMM after k_skepi
  float* ybuf = (float*)xab;          // wkv out: xab dead after k_skinny
  unsigned char* pairext = (unsigned char*)xwb;  // 32768*1664 = 54.5MB <= 66MB region
  // d_out second half holds z until k_fin writes v_first_out there.
  float* zbuf = (float*)d_out + ELq;
  float* yout = (float*)d_out;
  float* vfout = (float*)d_out + ELq;
  // W_o split-K partials span xrb..gbuf (32MB, all dead by the W_o GEMM)
  float* pWo0 = (float*)xrb;
  float* pWo1 = pWo0 + ELq;

  ConvJobs cj;
  cj.j[0]  = {W_r, WrB, Cq, Cq, 0};
  cj.j[1]  = {W_k, WkB, Cq, Cq, 0};
  cj.j[2]  = {W_v, WvB, Cq, Cq, 0};
  cj.j[3]  = {W_o, WoB, Cq, Cq, 0};
  cj.j[4]  = {w1, w1T, 2048, 64, 1};
  cj.j[5]  = {a1, a1T, 2048, 64, 1};
  cj.j[6]  = {v1, v1T, 2048, 32, 1};
  cj.j[7]  = {g1, g1T, 2048, 128, 1};
  cj.j[8]  = {w2, w2T, 64, 2048, 1};
  cj.j[9]  = {a2, a2T, 64, 2048, 1};
  cj.j[10] = {v2, v2T, 32, 2048, 1};
  cj.j[11] = {g2, g2T, 128, 2048, 1};
  cj.scal = scal;
  k_conv<<<dim3(1024, 1, 12), 256, 0, stream>>>(cj);

  k_prologue<<<ELq / 1024, 256, 0, stream>>>(x, x_r, x_w, x_k, x_v, x_a, x_g,
                                             xrb, xwb, xkb, xvb, xab, xgb);

  // skinny GEMMs: split-K x8 partials (one dispatch), then fused reduce+activation
  GJobs gsk;
  gsk.j[0] = {xwb, w1T, nullptr, pskw, nullptr, nullptr, nullptr, 256, 2048, 0};
  gsk.j[1] = {xab, a1T, nullptr, pska, nullptr, nullptr, nullptr, 256, 2048, 0};
  gsk.j[2] = {xvb, v1T, nullptr, pskv, nullptr, nullptr, nullptr, 256, 2048, 0};
  gsk.j[3] = {xgb, g1T, nullptr, pskg, nullptr, nullptr, nullptr, 256, 2048, 0};
  k_skinny<<<dim3(16, 8, 4), 256, 0, stream>>>(gsk);
  k_skepi<<<2304, 256, 0, stream>>>(pskw, pska, pskv, pskg, hwb, hab, hvb, hgb, scal + 0);

  // z4 GEMMs: w decay -> scanbuf; a sigmoid -> abuf; z absmax; g bf16
  GJobs g3j;
  g3j.j[0] = {hwb, w2T, w0, nullptr, nullptr, nullptr, nullptr, 64, 64, 10,
              nullptr, nullptr, nullptr, scanbuf};
  g3j.j[1] = {hab, a2T, a0, abuf, nullptr, nullptr, nullptr, 64, 64, 2};
  g3j.j[2] = {hvb, v2T, nullptr, zbuf, nullptr, scal + 1, nullptr, 32, 32, 7};
  g3j.j[3] = {hgb, g2T, nullptr, nullptr, gbuf, nullptr, nullptr, 128, 128, 4};
  k_gemm128<<<dim3(16, 16, 4), 256, 0, stream>>>(g3j);

  // r/k/v big GEMMs -> scanbuf (epi 12 / 11 / 9)
  GJobs g1j;
  g1j.j[0] = {xrb, WrB, nullptr, nullptr, nullptr, nullptr, nullptr, 2048, 2048, 12,
              nullptr, nullptr, nullptr, scanbuf};
  g1j.j[1] = {xkb, WkB, nullptr, nullptr, nullptr, nullptr, nullptr, 2048, 2048, 11,
              k_k, k_a, abuf, scanbuf};
  g1j.j[2] = {xvb, WvB, nullptr, nullptr, nullptr, scal + 2, vfirst, 2048, 2048, 9,
              nullptr, nullptr, nullptr, scanbuf};
  g1j.j[3] = g1j.j[0];
  k_gemm128<<<dim3(16, 16, 3), 256, 0, stream>>>(g1j);

  k_vfin<<<ELq / 1024, 256, 0, stream>>>(vfirst, zbuf, v0, scal, scanbuf);
  k_pre2<<<(64 * 512) / 4, 256, 0, stream>>>(scanbuf, pairext);
  k_wkv<<<16 * 2 * Hq, 64, 0, stream>>>(scanbuf, pairext, ybuf, scal + 3);
  k_epi1<<<(2 * Tq * Hq) / 4, 256, 0, stream>>>(ybuf, scanbuf, gbuf, lnw, lnb, r_k, ygb);

  // W_o GEMM: split-K x2 (2 blocks/CU), partials into aliased ws, then fused finish
  GJobs gfj;
  gfj.j[0] = {ygb, WoB, nullptr, pWo0, nullptr, nullptr, nullptr, 1024, 2048, 0};
  gfj.j[1] = {ygb + 1024, WoB + 1024, nullptr, pWo1, nullptr, nullptr, nullptr, 1024, 2048, 0};
  gfj.j[2] = gfj.j[0]; gfj.j[3] = gfj.j[0];
  k_gemm128<<<dim3(16, 16, 2), 256, 0, stream>>>(gfj);
  k_fin<<<ELq / 512, 256, 0, stream>>>(pWo0, pWo1, scal, yout, vfirst, vfout);
}

// Round 15
// 476.932 us; speedup vs baseline: 1.0301x; 1.0301x over previous
//
#include <hip/hip_runtime.h>
#include <hip/hip_bf16.h>

#define ELq 4194304   // B*T*C
#define Cq 2048
#define Tq 1024
#define Hq 32
#define Mq 2048       // B*T
#define SBYTES 1536   // scanbuf bytes per (head, t) step-block

typedef __attribute__((ext_vector_type(8))) short bf16x8;
typedef __attribute__((ext_vector_type(4))) float f32x4;

__device__ __forceinline__ unsigned short f2bu(float f) {
  union { float f; unsigned u; } v; v.f = f;
  unsigned r = v.u + 0x7fffu + ((v.u >> 16) & 1u);
  return (unsigned short)(r >> 16);
}
__device__ __forceinline__ float b2f(unsigned short u) {
  union { unsigned u; float f; } v; v.u = ((unsigned)u) << 16;
  return v.f;
}
__device__ __forceinline__ void gl_lds16(const void* g, void* l) {
  __builtin_amdgcn_global_load_lds((const __attribute__((address_space(1))) unsigned int*)g,
                                   (__attribute__((address_space(3))) unsigned int*)l, 16, 0, 0);
}

// DPP cross-lane add: x + lane-permuted x. VALU-pipe (no LDS), ~4-8 cyc.
template<int CTRL>
__device__ __forceinline__ float dpp_add(float x) {
  int t = __builtin_amdgcn_update_dpp(0, __builtin_bit_cast(int, x), CTRL, 0xF, 0xF, true);
  return x + __builtin_bit_cast(float, t);
}
// 16-lane sum broadcast (pure DPP, no LDS pipe)
__device__ __forceinline__ float red16(float x) {
  x = dpp_add<0xB1>(x); x = dpp_add<0x4E>(x);
  x = dpp_add<0x141>(x); x = dpp_add<0x140>(x);
  return x;
}

// scanbuf: per (head bh = b*32+h, t): 1536B block, all fp32
//   [0,256) r | [256,512) k | [512,768) a=-kk | [768,1024) b=kk*as
//   [1024,1280) w | [1280,1536) v
__device__ __forceinline__ size_t sb_off(int m, int c) {
  size_t blk = (size_t)(((m >> 10) * 32 + (c >> 6)) * 1024 + (m & 1023));
  return blk * SBYTES;
}

// ---------------- fused weight convert/transpose + token-shift prologue ----------------
struct ConvJob { const float* src; unsigned short* dst; int rows, cols, trans; };
struct ConvJobs { ConvJob j[12]; unsigned int* scal; };

__global__ void k_prep0(ConvJobs jobs, const float* __restrict__ x,
    const float* __restrict__ mr, const float* __restrict__ mw, const float* __restrict__ mk,
    const float* __restrict__ mv, const float* __restrict__ ma, const float* __restrict__ mg,
    unsigned short* __restrict__ xr, unsigned short* __restrict__ xw, unsigned short* __restrict__ xk,
    unsigned short* __restrict__ xv, unsigned short* __restrict__ xa, unsigned short* __restrict__ xg)
{
  if (blockIdx.z == 12) {
    // token-shift prologue, grid-stride (1024 blocks x 256 thr, 4 iters)
    for (int i4 = blockIdx.x * 256 + threadIdx.x; i4 < ELq / 4; i4 += 1024 * 256) {
      int i = i4 << 2;
      float4 xc = *(const float4*)(x + i);
      int t = (i >> 11) & (Tq - 1);
      float4 xp = make_float4(0.f, 0.f, 0.f, 0.f);
      if (t) xp = *(const float4*)(x + i - Cq);
      float4 dx = make_float4(xp.x - xc.x, xp.y - xc.y, xp.z - xc.z, xp.w - xc.w);
      int c = i & (Cq - 1);
      auto mix = [&](const float* __restrict__ m, unsigned short* __restrict__ o) {
        float4 mm = *(const float4*)(m + c);
        ushort4 u;
        u.x = f2bu(xc.x + dx.x * mm.x); u.y = f2bu(xc.y + dx.y * mm.y);
        u.z = f2bu(xc.z + dx.z * mm.z); u.w = f2bu(xc.w + dx.w * mm.w);
        *(ushort4*)(o + i) = u;
      };
      mix(mr, xr); mix(mw, xw); mix(mk, xk); mix(mv, xv); mix(ma, xa); mix(mg, xg);
    }
    return;
  }
  if (blockIdx.z == 0 && blockIdx.x == 0 && threadIdx.x < 8) jobs.scal[threadIdx.x] = 0u;
  ConvJob jb = jobs.j[blockIdx.z];
  int n4 = (jb.rows * jb.cols) >> 2;
  if (!jb.trans) {
    for (int i = blockIdx.x * blockDim.x + threadIdx.x; i < n4; i += gridDim.x * blockDim.x) {
      float4 v = ((const float4*)jb.src)[i];
      ushort4 o;
      o.x = f2bu(v.x); o.y = f2bu(v.y); o.z = f2bu(v.z); o.w = f2bu(v.w);
      ((ushort4*)jb.dst)[i] = o;
    }
  } else {
    // out[c][r] = src[r][c]; 4 rows per thread -> ushort4 store
    int rq = jb.rows >> 2;
    for (int i = blockIdx.x * blockDim.x + threadIdx.x; i < n4; i += gridDim.x * blockDim.x) {
      int c = i / rq;
      int r4 = (i - c * rq) << 2;
      const float* s = jb.src + (size_t)r4 * jb.cols + c;
      ushort4 u;
      u.x = f2bu(s[0]);
      u.y = f2bu(s[jb.cols]);
      u.z = f2bu(s[2 * jb.cols]);
      u.w = f2bu(s[3 * jb.cols]);
      *(ushort4*)(jb.dst + (size_t)c * jb.rows + r4) = u;
    }
  }
}

// ---------------- GEMM (A MxK row-major bf16, B NxK row-major bf16; C = A*B^T) ----------------
struct GJob {
  const unsigned short* A; const unsigned short* B;
  const float* bias; float* Cf; unsigned short* Cb;
  unsigned int* amax; const float* aux;
  int K; int ld; int epi;
  const float* kkw; const float* kaw; const float* asig;
  unsigned char* scan;
};
struct GJobs { GJob j[4]; };

// epi: 0 f32 | 1 f32+bias | 2 f32 sigmoid(v+bias) | 4 bf16 | 7 f32+absmax
//      9 v->scan+absmax(aux-v) | 10 w-decay->scan | 11 k-prep->scan | 12 r->scan
__device__ __forceinline__ void epi_store(int epi, float v, size_t o,
    float* Cf, unsigned short* Cb, const float* bias, int col, float& lmax)
{
  switch (epi) {
    case 0: Cf[o] = v; break;
    case 1: Cf[o] = v + bias[col]; break;
    case 2: Cf[o] = 1.f / (1.f + expf(-(v + bias[col]))); break;
    case 4: Cb[o] = f2bu(v); break;
    case 7: lmax = fmaxf(lmax, fabsf(v)); Cf[o] = v; break;
  }
}

// BK=64 via twin ping-pong [128][32] buffers (identical banking to BK=32; gl_lds
// stays linear). One barrier pair covers 2 K-subtiles.
__global__ __launch_bounds__(256, 2) void k_gemm128(GJobs jobs) {
  GJob jb = jobs.j[blockIdx.z];
  __shared__ __align__(16) unsigned short As[2][128 * 32];
  __shared__ __align__(16) unsigned short Bs[2][128 * 32];
  __shared__ float sred[4];
  const int tid = threadIdx.x, lane = tid & 63, wid = tid >> 6;
  const int wr = wid >> 1, wc = wid & 1;
  const int lin = blockIdx.y * 16 + blockIdx.x;
  const int swz = (lin & 7) * 32 + (lin >> 3);
  const int m0 = (swz >> 4) * 128, n0 = (swz & 15) * 128;
  const int K = jb.K, ld = jb.ld;
  const unsigned short* A = jb.A; const unsigned short* B = jb.B;
  f32x4 acc[4][4] = {};
  const int stg_row = (wid * 64 + lane) >> 2;
  const int stg_q   = lane & 3;
  const int stg_row2 = stg_row + 64;
  for (int k0 = 0; k0 < K; k0 += 64) {
    const bool h2 = (k0 + 32 < K);
    {
      int cw0 = wid * 64, cw1 = wid * 64 + 256;
      gl_lds16(A + (size_t)(m0 + stg_row) * ld + k0 + stg_q * 8, &As[0][cw0 * 8]);
      gl_lds16(B + (size_t)(n0 + stg_row) * ld + k0 + stg_q * 8, &Bs[0][cw0 * 8]);
      gl_lds16(A + (size_t)(m0 + stg_row2) * ld + k0 + stg_q * 8, &As[0][cw1 * 8]);
      gl_lds16(B + (size_t)(n0 + stg_row2) * ld + k0 + stg_q * 8, &Bs[0][cw1 * 8]);
      if (h2) {
        gl_lds16(A + (size_t)(m0 + stg_row) * ld + k0 + 32 + stg_q * 8, &As[1][cw0 * 8]);
        gl_lds16(B + (size_t)(n0 + stg_row) * ld + k0 + 32 + stg_q * 8, &Bs[1][cw0 * 8]);
        gl_lds16(A + (size_t)(m0 + stg_row2) * ld + k0 + 32 + stg_q * 8, &As[1][cw1 * 8]);
        gl_lds16(B + (size_t)(n0 + stg_row2) * ld + k0 + 32 + stg_q * 8, &Bs[1][cw1 * 8]);
      }
    }
    __syncthreads();
    const int kg = (lane >> 4) * 8;
    bf16x8 af[4], bq[4];
    #pragma unroll
    for (int mi = 0; mi < 4; ++mi)
      af[mi] = *(const bf16x8*)&As[0][(wr * 64 + mi * 16 + (lane & 15)) * 32 + kg];
    #pragma unroll
    for (int ni = 0; ni < 4; ++ni)
      bq[ni] = *(const bf16x8*)&Bs[0][(wc * 64 + ni * 16 + (lane & 15)) * 32 + kg];
    #pragma unroll
    for (int mi = 0; mi < 4; ++mi)
      #pragma unroll
      for (int ni = 0; ni < 4; ++ni)
        acc[mi][ni] = __builtin_amdgcn_mfma_f32_16x16x32_bf16(af[mi], bq[ni], acc[mi][ni], 0, 0, 0);
    if (h2) {
      #pragma unroll
      for (int mi = 0; mi < 4; ++mi)
        af[mi] = *(const bf16x8*)&As[1][(wr * 64 + mi * 16 + (lane & 15)) * 32 + kg];
      #pragma unroll
      for (int ni = 0; ni < 4; ++ni)
        bq[ni] = *(const bf16x8*)&Bs[1][(wc * 64 + ni * 16 + (lane & 15)) * 32 + kg];
      #pragma unroll
      for (int mi = 0; mi < 4; ++mi)
        #pragma unroll
        for (int ni = 0; ni < 4; ++ni)
          acc[mi][ni] = __builtin_amdgcn_mfma_f32_16x16x32_bf16(af[mi], bq[ni], acc[mi][ni], 0, 0, 0);
    }
    __syncthreads();
  }
  if (jb.epi == 12) {          // r -> scanbuf f32 @ +0
    #pragma unroll
    for (int mi = 0; mi < 4; ++mi)
      #pragma unroll
      for (int ni = 0; ni < 4; ++ni) {
        int col = n0 + wc * 64 + ni * 16 + (lane & 15);
        int row0 = m0 + wr * 64 + mi * 16 + ((lane >> 4) << 2);
        #pragma unroll
        for (int q = 0; q < 4; ++q)
          *(float*)(jb.scan + sb_off(row0 + q, col) + ((col & 63) << 2)) = acc[mi][ni][q];
      }
    return;
  }
  if (jb.epi == 10) {          // w decay -> scanbuf f32 @ +1024
    #pragma unroll
    for (int mi = 0; mi < 4; ++mi)
      #pragma unroll
      for (int ni = 0; ni < 4; ++ni) {
        int col = n0 + wc * 64 + ni * 16 + (lane & 15);
        int row0 = m0 + wr * 64 + mi * 16 + ((lane >> 4) << 2);
        float bc = jb.bias[col];
        #pragma unroll
        for (int q = 0; q < 4; ++q) {
          float wv = acc[mi][ni][q] + bc;
          float wlog = -log1pf(expf(-wv)) - 0.5f;
          *(float*)(jb.scan + sb_off(row0 + q, col) + 1024 + ((col & 63) << 2)) =
              expf(-expf(wlog));
        }
      }
    return;
  }
  if (jb.epi == 11) {          // k-prep -> scanbuf f32 (k@+256, -kk@+512, kk*as@+768)
    float kkwv[4], kawv[4]; int colv[4];
    #pragma unroll
    for (int ni = 0; ni < 4; ++ni) {
      colv[ni] = n0 + wc * 64 + ni * 16 + (lane & 15);
      kkwv[ni] = jb.kkw[colv[ni]];
      kawv[ni] = jb.kaw[colv[ni]];
    }
    #pragma unroll
    for (int mi = 0; mi < 4; ++mi) {
      #pragma unroll
      for (int q = 0; q < 4; ++q) {
        float kkv[4]; float ss = 0.f;
        #pragma unroll
        for (int ni = 0; ni < 4; ++ni) {
          kkv[ni] = acc[mi][ni][q] * kkwv[ni];
          ss += kkv[ni] * kkv[ni];
        }
        ss = red16(ss);
        float inv = 1.f / fmaxf(sqrtf(ss), 1e-12f);
        int row = m0 + wr * 64 + mi * 16 + ((lane >> 4) << 2) + q;
        #pragma unroll
        for (int ni = 0; ni < 4; ++ni) {
          int col = colv[ni];
          unsigned char* base = jb.scan + sb_off(row, col);
          int n4 = (col & 63) << 2;
          float kraw = acc[mi][ni][q];
          float kkn = kkv[ni] * inv;
          float as = jb.asig[(size_t)row * 2048 + col];
          *(float*)(base + 256 + n4) = kraw * (1.f + (as - 1.f) * kawv[ni]);
          *(float*)(base + 512 + n4) = -kkn;
          *(float*)(base + 768 + n4) = kkn * as;
        }
      }
    }
    return;
  }
  float lmax = 0.f;
  if (jb.epi == 9) {           // v raw -> scanbuf f32 @ +1280, absmax(aux - v)
    #pragma unroll
    for (int mi = 0; mi < 4; ++mi)
      #pragma unroll
      for (int ni = 0; ni < 4; ++ni) {
        int col = n0 + wc * 64 + ni * 16 + (lane & 15);
        int row0 = m0 + wr * 64 + mi * 16 + ((lane >> 4) << 2);
        #pragma unroll
        for (int q = 0; q < 4; ++q) {
          float v = acc[mi][ni][q];
          lmax = fmaxf(lmax, fabsf(jb.aux[(size_t)(row0 + q) * 2048 + col] - v));
          *(float*)(jb.scan + sb_off(row0 + q, col) + 1280 + ((col & 63) << 2)) = v;
        }
      }
  } else {
    #pragma unroll
    for (int mi = 0; mi < 4; ++mi)
      #pragma unroll
      for (int ni = 0; ni < 4; ++ni) {
        int col = n0 + wc * 64 + ni * 16 + (lane & 15);
        int row = m0 + wr * 64 + mi * 16 + ((lane >> 4) << 2);
        #pragma unroll
        for (int q = 0; q < 4; ++q)
          epi_store(jb.epi, acc[mi][ni][q], (size_t)(row + q) * 2048 + col,
                    jb.Cf, jb.Cb, jb.bias, col, lmax);
      }
  }
  if (jb.epi == 7 || jb.epi == 9) {
    #pragma unroll
    for (int o = 32; o; o >>= 1) lmax = fmaxf(lmax, __shfl_xor(lmax, o));
    if (lane == 0) sred[wid] = lmax;
    __syncthreads();
    if (tid == 0)
      atomicMax(jb.amax, __float_as_uint(fmaxf(fmaxf(sred[0], sred[1]), fmaxf(sred[2], sred[3]))));
  }
}

// ---------------- skinny GEMMs, split-K x8, ALL FOUR in one dispatch ----------------
template<int TBN>
__device__ __forceinline__ void sk_body(const GJob& jb,
    unsigned short* __restrict__ As, unsigned short* __restrict__ Bs) {
  const int tid = threadIdx.x, lane = tid & 63, wid = tid >> 6;
  const int m0 = blockIdx.x * 128;
  const int koff = blockIdx.y * 256;
  const int ld = jb.ld;
  constexpr int NF = TBN / 16;
  const unsigned short* A = jb.A + koff;
  const unsigned short* B = jb.B + koff;
  float* out = jb.Cf + (size_t)blockIdx.y * (2048 * TBN);
  f32x4 acc[2][NF] = {};
  for (int k0 = 0; k0 < 256; k0 += 32) {
    for (int cw = wid * 64; cw < 512; cw += 256) {
      int c = cw + lane; int row = c >> 2, q = c & 3;
      gl_lds16(A + (size_t)(m0 + row) * ld + k0 + q * 8, &As[cw * 8]);
    }
    for (int cw = wid * 64; cw < TBN * 4; cw += 256) {
      int c = cw + lane; int row = c >> 2, q = c & 3;
      gl_lds16(B + (size_t)row * ld + k0 + q * 8, &Bs[cw * 8]);
    }
    __syncthreads();
    const int kg = (lane >> 4) * 8;
    bf16x8 af[2], bq[NF];
    #pragma unroll
    for (int mi = 0; mi < 2; ++mi)
      af[mi] = *(const bf16x8*)&As[(wid * 32 + mi * 16 + (lane & 15)) * 32 + kg];
    #pragma unroll
    for (int ni = 0; ni < NF; ++ni)
      bq[ni] = *(const bf16x8*)&Bs[(ni * 16 + (lane & 15)) * 32 + kg];
    #pragma unroll
    for (int mi = 0; mi < 2; ++mi)
      #pragma unroll
      for (int ni = 0; ni < NF; ++ni)
        acc[mi][ni] = __builtin_amdgcn_mfma_f32_16x16x32_bf16(af[mi], bq[ni], acc[mi][ni], 0, 0, 0);
    __syncthreads();
  }
  #pragma unroll
  for (int mi = 0; mi < 2; ++mi)
    #pragma unroll
    for (int ni = 0; ni < NF; ++ni) {
      int col = ni * 16 + (lane & 15);
      int row = m0 + wid * 32 + mi * 16 + ((lane >> 4) << 2);
      #pragma unroll
      for (int q = 0; q < 4; ++q)
        out[(size_t)(row + q) * TBN + col] = acc[mi][ni][q];
    }
}

__global__ __launch_bounds__(256, 2) void k_skinny(GJobs jobs) {
  __shared__ __align__(16) unsigned short As[128 * 32];
  __shared__ __align__(16) unsigned short Bs[128 * 32];
  switch (blockIdx.z) {
    case 0:  sk_body<64>(jobs.j[0], As, Bs); break;
    case 1:  sk_body<64>(jobs.j[1], As, Bs); break;
    case 2:  sk_body<32>(jobs.j[2], As, Bs); break;
    default: sk_body<128>(jobs.j[3], As, Bs); break;
  }
}

// ---------------- split-K reduce + activations for the 4 skinny GEMMs ----------------
__global__ void k_skepi(const float* __restrict__ pw, const float* __restrict__ pa,
                        const float* __restrict__ pv, const float* __restrict__ pg,
                        unsigned short* __restrict__ hw, unsigned short* __restrict__ ha,
                        unsigned short* __restrict__ hv, unsigned short* __restrict__ hg,
                        unsigned int* __restrict__ amax) {
  int i = blockIdx.x * 256 + threadIdx.x;    // 0 .. 589823
  const float* src; unsigned short* dst; int stride, mode, loc;
  if (i < 131072)      { src = pw; dst = hw; stride = 131072; mode = 0; loc = i; }
  else if (i < 262144) { src = pa; dst = ha; stride = 131072; mode = 1; loc = i - 131072; }
  else if (i < 327680) { src = pv; dst = hv; stride = 65536;  mode = 2; loc = i - 262144; }
  else                 { src = pg; dst = hg; stride = 262144; mode = 3; loc = i - 327680; }
  float s = 0.f;
  #pragma unroll
  for (int sp = 0; sp < 8; ++sp) s += src[loc + (size_t)sp * stride];
  float lmax = 0.f, o;
  switch (mode) {
    case 0: o = tanhf(s); break;
    case 1: o = s; break;
    case 2: o = s; lmax = fabsf(s); break;
    default: o = 1.f / (1.f + expf(-s)); break;
  }
  dst[loc] = f2bu(o);
  #pragma unroll
  for (int of = 32; of; of >>= 1) lmax = fmaxf(lmax, __shfl_xor(lmax, of));
  if ((threadIdx.x & 63) == 0 && lmax > 0.f) atomicMax(amax, __float_as_uint(lmax));
}

// ---------------- v residual gating, IN PLACE on scanbuf @ +1280 ----------------
__global__ void k_vfin(const float* __restrict__ vf, const float* __restrict__ z,
                       const float* __restrict__ v0c, const unsigned int* __restrict__ sc,
                       unsigned char* __restrict__ scan) {
  int i4 = blockIdx.x * 256 + threadIdx.x;
  if (i4 >= ELq / 4) return;
  int i = i4 << 2;
  float m1 = fmaxf(__uint_as_float(sc[0]), 1.f);
  float m2 = fmaxf(__uint_as_float(sc[1]) / m1, 1.f);
  float inv12 = 1.f / (m1 * m2);
  float invvd = 1.f / fmaxf(__uint_as_float(sc[2]), 1.f);
  int m = i >> 11;
  int c = i & (Cq - 1);
  float* vp = (float*)(scan + sb_off(m, c) + 1280 + ((c & 63) << 2));
  float4 zv = *(const float4*)(z + i);
  float4 vv = *(const float4*)vp;
  float4 fv = *(const float4*)(vf + i);
  float4 v0v = *(const float4*)(v0c + c);
  float4 o;
  #pragma unroll
  for (int j = 0; j < 4; ++j) {
    float gx = (&v0v.x)[j] + (&zv.x)[j] * inv12;
    gx = fminf(fmaxf(gx, -16.f), 16.f);
    float gate = 1.f / (1.f + expf(-gx));
    float vr = (&vv.x)[j];
    (&o.x)[j] = vr + ((&fv.x)[j] - vr) * (gate * invvd);
  }
  *(float4*)vp = o;
}

// ---------------- wkv7 scan: row-parallel, packed fp32 scanbuf, global->VGPR ----
// (Round-11/13 proven structure: 4 rows/wave, 16 lanes/row, pure-DPP reductions,
// prefetch distance 8 via 8 named buffers, unroll x8, 1024 blocks.)
struct SRg { float4 r, k, a, b, w; float v; };

__device__ __forceinline__ void ld_g(SRg& R, const unsigned char* p, int cl16, int row) {
  R.r = *(const float4*)(p + cl16);
  R.k = *(const float4*)(p + 256 + cl16);
  R.a = *(const float4*)(p + 512 + cl16);
  R.b = *(const float4*)(p + 768 + cl16);
  R.w = *(const float4*)(p + 1024 + cl16);
  R.v = *(const float*)(p + 1280 + row * 4);
}

__device__ __forceinline__ void wkv_step(const SRg& R, float S[4], float& ymx,
    float* __restrict__ y, size_t yoff, int lane) {
  float sa = (S[0]*R.a.x + S[1]*R.a.y) + (S[2]*R.a.z + S[3]*R.a.w);
  sa = red16(sa);
  float vi = R.v;
  float s0 = S[0]*R.w.x + (sa*R.b.x + vi*R.k.x);
  float s1 = S[1]*R.w.y + (sa*R.b.y + vi*R.k.y);
  float s2 = S[2]*R.w.z + (sa*R.b.z + vi*R.k.z);
  float s3 = S[3]*R.w.w + (sa*R.b.w + vi*R.k.w);
  S[0]=s0; S[1]=s1; S[2]=s2; S[3]=s3;
  float yp = (s0*R.r.x + s1*R.r.y) + (s2*R.r.z + s3*R.r.w);
  yp = red16(yp);
  if ((lane & 15) == 0) {
    y[yoff] = yp;
    ymx = fmaxf(ymx, fabsf(yp));
  }
}

__global__ __launch_bounds__(64, 1) void k_wkv(const unsigned char* __restrict__ scan,
    float* __restrict__ y, unsigned int* __restrict__ ymax) {
  const int lane = threadIdx.x;
  const int bh = blockIdx.x & 63;          // b*32 + h — same-head blocks share an XCD
  const int rq = blockIdx.x >> 6;          // row quad (0..15)
  const int row = rq * 4 + (lane >> 4);
  const int cl16 = (lane & 15) * 16;
  float S[4];
  #pragma unroll
  for (int q = 0; q < 4; ++q) S[q] = 0.f;
  const unsigned char* gs = scan + (size_t)bh * Tq * SBYTES;
  const size_t ybase = (size_t)(bh >> 5) * Tq * Cq + (size_t)(bh & 31) * 64 + row;

  SRg R0, R1, R2, R3, R4, R5, R6, R7;
  ld_g(R0, gs,              cl16, row);
  ld_g(R1, gs + SBYTES,     cl16, row);
  ld_g(R2, gs + 2 * SBYTES, cl16, row);
  ld_g(R3, gs + 3 * SBYTES, cl16, row);
  ld_g(R4, gs + 4 * SBYTES, cl16, row);
  ld_g(R5, gs + 5 * SBYTES, cl16, row);
  ld_g(R6, gs + 6 * SBYTES, cl16, row);
  ld_g(R7, gs + 7 * SBYTES, cl16, row);

  float ymx = 0.f;
  for (int t = 0; t < Tq; t += 8) {
    int n0 = (t + 8  < Tq) ? t + 8  : Tq - 1;
    int n1 = (t + 9  < Tq) ? t + 9  : Tq - 1;
    int n2 = (t + 10 < Tq) ? t + 10 : Tq - 1;
    int n3 = (t + 11 < Tq) ? t + 11 : Tq - 1;
    int n4 = (t + 12 < Tq) ? t + 12 : Tq - 1;
    int n5 = (t + 13 < Tq) ? t + 13 : Tq - 1;
    int n6 = (t + 14 < Tq) ? t + 14 : Tq - 1;
    int n7 = (t + 15 < Tq) ? t + 15 : Tq - 1;
    wkv_step(R0, S, ymx, y, ybase + (size_t)t * Cq, lane);
    ld_g(R0, gs + (size_t)n0 * SBYTES, cl16, row);
    wkv_step(R1, S, ymx, y, ybase + (size_t)(t + 1) * Cq, lane);
    ld_g(R1, gs + (size_t)n1 * SBYTES, cl16, row);
    wkv_step(R2, S, ymx, y, ybase + (size_t)(t + 2) * Cq, lane);
    ld_g(R2, gs + (size_t)n2 * SBYTES, cl16, row);
    wkv_step(R3, S, ymx, y, ybase + (size_t)(t + 3) * Cq, lane);
    ld_g(R3, gs + (size_t)n3 * SBYTES, cl16, row);
    wkv_step(R4, S, ymx, y, ybase + (size_t)(t + 4) * Cq, lane);
    ld_g(R4, gs + (size_t)n4 * SBYTES, cl16, row);
    wkv_step(R5, S, ymx, y, ybase + (size_t)(t + 5) * Cq, lane);
    ld_g(R5, gs + (size_t)n5 * SBYTES, cl16, row);
    wkv_step(R6, S, ymx, y, ybase + (size_t)(t + 6) * Cq, lane);
    ld_g(R6, gs + (size_t)n6 * SBYTES, cl16, row);
    wkv_step(R7, S, ymx, y, ybase + (size_t)(t + 7) * Cq, lane);
    ld_g(R7, gs + (size_t)n7 * SBYTES, cl16, row);
  }
  #pragma unroll
  for (int o = 32; o; o >>= 1) ymx = fmaxf(ymx, __shfl_xor(ymx, o));
  if (lane == 0) atomicMax(ymax, __float_as_uint(ymx));
}

// ---------------- groupnorm + bonus + gate ----------------
__global__ __launch_bounds__(256) void k_epi1(const float* __restrict__ y,
    const unsigned char* __restrict__ scan, const unsigned short* __restrict__ g,
    const float* __restrict__ lnw, const float* __restrict__ lnb, const float* __restrict__ rk,
    unsigned short* __restrict__ yg) {
  int wid = threadIdx.x >> 6, lane = threadIdx.x & 63;
  int idx = blockIdx.x * 4 + wid;            // (b*Tq + t)*32 + h
  size_t off = (size_t)idx * 64 + lane;
  int c = ((idx & (Hq - 1)) << 6) | lane;
  int b = idx >> 15, t = (idx >> 5) & 1023, h = idx & 31;
  const unsigned char* so = scan + (size_t)((b * 32 + h) * 1024 + t) * SBYTES;
  float yv = y[off];
  float s = yv;
  #pragma unroll
  for (int o = 32; o; o >>= 1) s += __shfl_xor(s, o);
  float mu = s * (1.f / 64.f);
  float d = yv - mu;
  float vs = d * d;
  #pragma unroll
  for (int o = 32; o; o >>= 1) vs += __shfl_xor(vs, o);
  float yn = d / sqrtf(vs * (1.f / 64.f) + 6.4e-4f);
  float yo = yn * lnw[c] + lnb[c];
  float rv = *(const float*)(so + lane * 4);
  float kv = *(const float*)(so + 256 + lane * 4);
  float vv = *(const float*)(so + 1280 + lane * 4);
  float bon = rv * kv * rk[c];
  #pragma unroll
  for (int o = 32; o; o >>= 1) bon += __shfl_xor(bon, o);
  yo += bon * vv;
  yg[off] = f2bu(yo * b2f(g[off]));
}

// ---------------- fused finish: yout = (p0+p1)*scale ; vfout = vf*scale ----------------
__global__ void k_fin(const float* __restrict__ p0, const float* __restrict__ p1,
                      const unsigned int* __restrict__ sc, float* __restrict__ yout,
                      const float* __restrict__ vf, float* __restrict__ vfout) {
  int i = blockIdx.x * 256 + threadIdx.x;
  float s = (__uint_as_float(sc[3]) > 179.2f) ? 0.5f : 1.f;
  if (i < ELq / 4) {
    float4 a = ((const float4*)p0)[i];
    float4 b = ((const float4*)p1)[i];
    ((float4*)yout)[i] = make_float4((a.x + b.x) * s, (a.y + b.y) * s,
                                     (a.z + b.z) * s, (a.w + b.w) * s);
  } else {
    int j = i - ELq / 4;
    float4 vv = ((const float4*)vf)[j];
    ((float4*)vfout)[j] = make_float4(vv.x * s, vv.y * s, vv.z * s, vv.w * s);
  }
}

extern "C" void kernel_launch(void* const* d_in, const int* in_sizes, int n_in,
                              void* d_out, int out_size, void* d_ws, size_t ws_size,
                              hipStream_t stream) {
  const float* x      = (const float*)d_in[0];
  const float* vfirst = (const float*)d_in[1];
  const float* x_r = (const float*)d_in[2];
  const float* x_w = (const float*)d_in[3];
  const float* x_k = (const float*)d_in[4];
  const float* x_v = (const float*)d_in[5];
  const float* x_a = (const float*)d_in[6];
  const float* x_g = (const float*)d_in[7];
  const float* w0 = (const float*)d_in[8];
  const float* w1 = (const float*)d_in[9];
  const float* w2 = (const float*)d_in[10];
  const float* a0 = (const float*)d_in[11];
  const float* a1 = (const float*)d_in[12];
  const float* a2 = (const float*)d_in[13];
  const float* v0 = (const float*)d_in[14];
  const float* v1 = (const float*)d_in[15];
  const float* v2 = (const float*)d_in[16];
  const float* g1 = (const float*)d_in[17];
  const float* g2 = (const float*)d_in[18];
  const float* k_k = (const float*)d_in[19];
  const float* k_a = (const float*)d_in[20];
  const float* r_k = (const float*)d_in[21];
  const float* W_r = (const float*)d_in[22];
  const float* W_k = (const float*)d_in[23];
  const float* W_v = (const float*)d_in[24];
  const float* W_o = (const float*)d_in[25];
  const float* lnw = (const float*)d_in[26];
  const float* lnb = (const float*)d_in[27];

  char* ws = (char*)d_ws;
  size_t off = 0;
  auto alloc = [&](size_t bytes) -> void* {
    void* p = ws + off; off += (bytes + 255) & ~(size_t)255; return p;
  };
  unsigned int* scal = (unsigned int*)alloc(256);      // [M1, MZ, MVD, MY]
  unsigned char* scanbuf = (unsigned char*)alloc((size_t)64 * Tq * SBYTES);  // 96MB
  unsigned short* xrb = (unsigned short*)alloc((size_t)ELq * 2);
  unsigned short* xwb = (unsigned short*)alloc((size_t)ELq * 2);
  unsigned short* xkb = (unsigned short*)alloc((size_t)ELq * 2);
  unsigned short* xvb = (unsigned short*)alloc((size_t)ELq * 2);
  unsigned short* xab = (unsigned short*)alloc((size_t)ELq * 2);
  unsigned short* xgb = (unsigned short*)alloc((size_t)ELq * 2);
  unsigned short* gbuf = (unsigned short*)alloc((size_t)ELq * 2);
  unsigned short* ygb  = (unsigned short*)alloc((size_t)ELq * 2);
  unsigned short* WrB = (unsigned short*)alloc((size_t)ELq * 2);
  unsigned short* WkB = (unsigned short*)alloc((size_t)ELq * 2);
  unsigned short* WvB = (unsigned short*)alloc((size_t)ELq * 2);
  unsigned short* WoB = (unsigned short*)alloc((size_t)ELq * 2);
  unsigned short* w1T = (unsigned short*)alloc(64 * 2048 * 2);
  unsigned short* a1T = (unsigned short*)alloc(64 * 2048 * 2);
  unsigned short* v1T = (unsigned short*)alloc(32 * 2048 * 2);
  unsigned short* g1T = (unsigned short*)alloc(128 * 2048 * 2);
  unsigned short* w2T = (unsigned short*)alloc(2048 * 64 * 2);
  unsigned short* a2T = (unsigned short*)alloc(2048 * 64 * 2);
  unsigned short* v2T = (unsigned short*)alloc(2048 * 32 * 2);
  unsigned short* g2T = (unsigned short*)alloc(2048 * 128 * 2);
  unsigned short* hwb = (unsigned short*)alloc((size_t)Mq * 64 * 2);
  unsigned short* hab = (unsigned short*)alloc((size_t)Mq * 64 * 2);
  unsigned short* hvb = (unsigned short*)alloc((size_t)Mq * 32 * 2);
  unsigned short* hgb = (unsigned short*)alloc((size_t)Mq * 128 * 2);
  float* pskw = (float*)alloc((size_t)8 * Mq * 64 * 4);
  float* pska = (float*)alloc((size_t)8 * Mq * 64 * 4);
  float* pskv = (float*)alloc((size_t)8 * Mq * 32 * 4);
  float* pskg = (float*)alloc((size_t)8 * Mq * 128 * 4);
  // Aliases (dead-buffer reuse, stream-order checked):
  //   abuf (sigmoid-a f32, 16MB): written by z4 GEMM AFTER k_skepi frees psk region.
  float* abuf = pskw;
  //   ybuf (wkv out f32, 16MB): xab+xgb are dead after k_skinny; k_wkv writes later.
  float* ybuf = (float*)xab;
  // d_out second half holds z until k_fin writes v_first_out there.
  float* zbuf = (float*)d_out + ELq;
  float* yout = (float*)d_out;
  float* vfout = (float*)d_out + ELq;
  // W_o split-K partials alias xrb..xvb (dead by then): 2 x ELq floats = 4 x ELq bf16
  float* pWo0 = (float*)xrb;
  float* pWo1 = pWo0 + ELq;

  ConvJobs cj;
  cj.j[0]  = {W_r, WrB, Cq, Cq, 0};
  cj.j[1]  = {W_k, WkB, Cq, Cq, 0};
  cj.j[2]  = {W_v, WvB, Cq, Cq, 0};
  cj.j[3]  = {W_o, WoB, Cq, Cq, 0};
  cj.j[4]  = {w1, w1T, 2048, 64, 1};
  cj.j[5]  = {a1, a1T, 2048, 64, 1};
  cj.j[6]  = {v1, v1T, 2048, 32, 1};
  cj.j[7]  = {g1, g1T, 2048, 128, 1};
  cj.j[8]  = {w2, w2T, 64, 2048, 1};
  cj.j[9]  = {a2, a2T, 64, 2048, 1};
  cj.j[10] = {v2, v2T, 32, 2048, 1};
  cj.j[11] = {g2, g2T, 128, 2048, 1};
  cj.scal = scal;
  // fused: conv jobs (z 0..11) + token-shift prologue (z 12)
  k_prep0<<<dim3(1024, 1, 13), 256, 0, stream>>>(cj, x, x_r, x_w, x_k, x_v, x_a, x_g,
                                                 xrb, xwb, xkb, xvb, xab, xgb);

  // skinny GEMMs: split-K x8 partials (one dispatch, 4 jobs), then fused reduce+activation
  GJobs gsk;
  gsk.j[0] = {xwb, w1T, nullptr, pskw, nullptr, nullptr, nullptr, 256, 2048, 0};
  gsk.j[1] = {xab, a1T, nullptr, pska, nullptr, nullptr, nullptr, 256, 2048, 0};
  gsk.j[2] = {xvb, v1T, nullptr, pskv, nullptr, nullptr, nullptr, 256, 2048, 0};
  gsk.j[3] = {xgb, g1T, nullptr, pskg, nullptr, nullptr, nullptr, 256, 2048, 0};
  k_skinny<<<dim3(16, 8, 4), 256, 0, stream>>>(gsk);
  k_skepi<<<2304, 256, 0, stream>>>(pskw, pska, pskv, pskg, hwb, hab, hvb, hgb, scal + 0);

  // z4 GEMMs: w decay -> scanbuf (epi 10); a sigmoid -> abuf (aliased over psk);
  // z absmax; g bf16
  GJobs g3j;
  g3j.j[0] = {hwb, w2T, w0, nullptr, nullptr, nullptr, nullptr, 64, 64, 10,
              nullptr, nullptr, nullptr, scanbuf};
  g3j.j[1] = {hab, a2T, a0, abuf, nullptr, nullptr, nullptr, 64, 64, 2};
  g3j.j[2] = {hvb, v2T, nullptr, zbuf, nullptr, scal + 1, nullptr, 32, 32, 7};
  g3j.j[3] = {hgb, g2T, nullptr, nullptr, gbuf, nullptr, nullptr, 128, 128, 4};
  k_gemm128<<<dim3(16, 16, 4), 256, 0, stream>>>(g3j);

  // r/k/v big GEMMs; r -> scanbuf (epi 12); k-prep -> scanbuf (epi 11);
  // v raw -> scanbuf + absmax(v_first - v) (epi 9)
  GJobs g1j;
  g1j.j[0] = {xrb, WrB, nullptr, nullptr, nullptr, nullptr, nullptr, 2048, 2048, 12,
              nullptr, nullptr, nullptr, scanbuf};
  g1j.j[1] = {xkb, WkB, nullptr, nullptr, nullptr, nullptr, nullptr, 2048, 2048, 11,
              k_k, k_a, abuf, scanbuf};
  g1j.j[2] = {xvb, WvB, nullptr, nullptr, nullptr, scal + 2, vfirst, 2048, 2048, 9,
              nullptr, nullptr, nullptr, scanbuf};
  g1j.j[3] = g1j.j[0];
  k_gemm128<<<dim3(16, 16, 3), 256, 0, stream>>>(g1j);

  k_vfin<<<ELq / 1024, 256, 0, stream>>>(vfirst, zbuf, v0, scal, scanbuf);
  k_wkv<<<16 * 2 * Hq, 64, 0, stream>>>(scanbuf, ybuf, scal + 3);
  k_epi1<<<(2 * Tq * Hq) / 4, 256, 0, stream>>>(ybuf, scanbuf, gbuf, lnw, lnb, r_k, ygb);

  // W_o GEMM: split-K x2 (2 blocks/CU), partials into aliased ws, then fused finish
  GJobs gfj;
  gfj.j[0] = {ygb, WoB, nullptr, pWo0, nullptr, nullptr, nullptr, 1024, 2048, 0};
  gfj.j[1] = {ygb + 1024, WoB + 1024, nullptr, pWo1, nullptr, nullptr, nullptr, 1024, 2048, 0};
  gfj.j[2] = gfj.j[0]; gfj.j[3] = gfj.j[0];
  k_gemm128<<<dim3(16, 16, 2), 256, 0, stream>>>(gfj);
  k_fin<<<ELq / 512, 256, 0, stream>>>(pWo0, pWo1, scal, yout, vfirst, vfout);
}